// Round 11
// baseline (301.910 us; speedup 1.0000x reference)
//
#include <hip/hip_runtime.h>
#include <math.h>

typedef __attribute__((ext_vector_type(8))) short short8;
typedef __attribute__((ext_vector_type(4))) float floatx4;

// ---------------- bf16 helpers ----------------

__device__ __forceinline__ unsigned short f2bf(float f) {
    unsigned int u = __float_as_uint(f);
    unsigned int r = (u + 0x7fffu + ((u >> 16) & 1u)) >> 16;  // RNE
    return (unsigned short)r;
}
__device__ __forceinline__ float bfu_lo(unsigned int u) {
    return __uint_as_float(u << 16);
}
__device__ __forceinline__ float bfu_hi(unsigned int u) {
    return __uint_as_float(u & 0xffff0000u);
}

// ---------------- precompute ----------------

// init deg/cnt/cursor/gsum/done + both weight transposes (one launch)
__global__ void k_init_wt(float* __restrict__ deg, int* __restrict__ cnt,
                          int* __restrict__ cursor, int N,
                          const float* __restrict__ W2, unsigned short* __restrict__ WT2,
                          int K2, int F2,
                          const float* __restrict__ W3, unsigned short* __restrict__ WT3,
                          int K3, int F3,
                          float* __restrict__ gsum, int* __restrict__ done, int G) {
    int i = blockIdx.x * blockDim.x + threadIdx.x;
    if (i < N) { deg[i] = 1.0f; cnt[i] = 0; cursor[i] = 0; }
    if (i < G) gsum[i] = 0.f;
    if (i == 0) *done = 0;
    int n2 = K2 * F2;
    if (i < n2) {
        int k = i / F2, n = i % F2;
        WT2[(size_t)n * K2 + k] = f2bf(W2[i]);
    } else {
        int j = i - n2;
        if (j < K3 * F3) {
            int k = j / F3, n = j % F3;
            WT3[(size_t)n * K3 + k] = f2bf(W3[j]);
        }
    }
}

__global__ void k_hist_deg(const int* __restrict__ dst, const float* __restrict__ ew,
                           float* __restrict__ deg, int* __restrict__ cnt, int E) {
    int e = blockIdx.x * blockDim.x + threadIdx.x;
    if (e < E) {
        int d = dst[e];
        atomicAdd(&deg[d], ew[e]);
        atomicAdd(&cnt[d], 1);
    }
}

// fused: deg -> rsqrt in place (dinv) AND per-block cnt sums for the scan
__global__ __launch_bounds__(256) void k_dinv_scana(float* __restrict__ deg,
                                                    const int* __restrict__ cnt,
                                                    int* __restrict__ bsum, int N) {
    int b = blockIdx.x, t = threadIdx.x;
    int base = b * 1024 + t * 4;
    int s = 0;
#pragma unroll
    for (int j = 0; j < 4; ++j) {
        int i = base + j;
        if (i < N) { deg[i] = rsqrtf(deg[i]); s += cnt[i]; }
    }
    __shared__ int sh[256];
    sh[t] = s; __syncthreads();
    for (int st = 128; st > 0; st >>= 1) { if (t < st) sh[t] += sh[t + st]; __syncthreads(); }
    if (t == 0) bsum[b] = sh[0];
}

// scan_c with inlined cross-block offset
__global__ __launch_bounds__(256) void k_scan_c(const int* __restrict__ cnt,
                                                const int* __restrict__ bsum,
                                                int* __restrict__ row_start, int N, int nb) {
    int b = blockIdx.x, t = threadIdx.x;
    __shared__ int sh[256];
    __shared__ int boffs;

    if (t < 64) {
        int s = 0;
        for (int i = t; i < b; i += 64) s += bsum[i];
#pragma unroll
        for (int off = 32; off > 0; off >>= 1) s += __shfl_down(s, off);
        if (t == 0) boffs = s;
    }
    __syncthreads();

    int base = b * 1024 + t * 4;
    int v[4]; int s = 0;
#pragma unroll
    for (int j = 0; j < 4; ++j) { int i = base + j; v[j] = (i < N) ? cnt[i] : 0; s += v[j]; }
    sh[t] = s; __syncthreads();
    for (int off = 1; off < 256; off <<= 1) {
        int x = (t >= off) ? sh[t - off] : 0;
        __syncthreads();
        sh[t] += x;
        __syncthreads();
    }
    int excl = sh[t] - s + boffs;
#pragma unroll
    for (int j = 0; j < 4; ++j) {
        int i = base + j;
        if (i < N) row_start[i] = excl;
        excl += v[j];
        if (i == N - 1) row_start[N] = excl;
    }
}

// fused: CSR scatter + norm computation
__global__ void k_scatter_norm(const int* __restrict__ src, const int* __restrict__ dst,
                               const float* __restrict__ ew, const float* __restrict__ dinv,
                               const int* __restrict__ row_start, int* __restrict__ cursor,
                               int* __restrict__ esrc, float* __restrict__ enorm, int E) {
    int e = blockIdx.x * blockDim.x + threadIdx.x;
    if (e >= E) return;
    int d = dst[e], s = src[e];
    int pos = row_start[d] + atomicAdd(&cursor[d], 1);
    esrc[pos] = s;
    enorm[pos] = dinv[s] * ew[e] * dinv[d];
}

// ---------------- layer 1: fused agg(x)[N,8] + fp32 GEMM(K=8) -> relu -> h1 bf16 ----------------

__global__ __launch_bounds__(256) void k_l1_gemm(
    const float* __restrict__ x, const float* __restrict__ dinv,
    const int* __restrict__ esrc, const float* __restrict__ enorm,
    const int* __restrict__ row_start, const float* __restrict__ W1,
    const float* __restrict__ b1, unsigned short* __restrict__ h1, int N) {
    __shared__ float As[8][132];
    __shared__ float Bs[8][128];

    int tid = threadIdx.x;
    int bm = blockIdx.x * 128;

#pragma unroll
    for (int i = tid; i < 1024; i += 256) Bs[i >> 7][i & 127] = W1[i];

    if (tid < 128) {
        int n = bm + tid;
        float a[8] = {0, 0, 0, 0, 0, 0, 0, 0};
        if (n < N) {
            float dv = dinv[n];
            float dv2 = dv * dv;
            float4 v0 = *(const float4*)&x[(size_t)n * 8];
            float4 v1 = *(const float4*)&x[(size_t)n * 8 + 4];
            a[0] = v0.x * dv2; a[1] = v0.y * dv2; a[2] = v0.z * dv2; a[3] = v0.w * dv2;
            a[4] = v1.x * dv2; a[5] = v1.y * dv2; a[6] = v1.z * dv2; a[7] = v1.w * dv2;
            int j0 = row_start[n], j1 = row_start[n + 1];
            // 4-wide MLP gather: 4 independent row loads in flight
            for (int b = j0; b < j1; b += 4) {
                int i1 = (b + 1 < j1) ? b + 1 : b;
                int i2 = (b + 2 < j1) ? b + 2 : b;
                int i3 = (b + 3 < j1) ? b + 3 : b;
                float w0 = enorm[b];
                float w1 = (b + 1 < j1) ? enorm[i1] : 0.f;
                float w2 = (b + 2 < j1) ? enorm[i2] : 0.f;
                float w3 = (b + 3 < j1) ? enorm[i3] : 0.f;
                int s0 = esrc[b], s1 = esrc[i1], s2 = esrc[i2], s3 = esrc[i3];
                float4 p0 = *(const float4*)&x[(size_t)s0 * 8];
                float4 q0 = *(const float4*)&x[(size_t)s0 * 8 + 4];
                float4 p1 = *(const float4*)&x[(size_t)s1 * 8];
                float4 q1 = *(const float4*)&x[(size_t)s1 * 8 + 4];
                float4 p2 = *(const float4*)&x[(size_t)s2 * 8];
                float4 q2 = *(const float4*)&x[(size_t)s2 * 8 + 4];
                float4 p3 = *(const float4*)&x[(size_t)s3 * 8];
                float4 q3 = *(const float4*)&x[(size_t)s3 * 8 + 4];
                a[0] += w0 * p0.x + w1 * p1.x + w2 * p2.x + w3 * p3.x;
                a[1] += w0 * p0.y + w1 * p1.y + w2 * p2.y + w3 * p3.y;
                a[2] += w0 * p0.z + w1 * p1.z + w2 * p2.z + w3 * p3.z;
                a[3] += w0 * p0.w + w1 * p1.w + w2 * p2.w + w3 * p3.w;
                a[4] += w0 * q0.x + w1 * q1.x + w2 * q2.x + w3 * q3.x;
                a[5] += w0 * q0.y + w1 * q1.y + w2 * q2.y + w3 * q3.y;
                a[6] += w0 * q0.z + w1 * q1.z + w2 * q2.z + w3 * q3.z;
                a[7] += w0 * q0.w + w1 * q1.w + w2 * q2.w + w3 * q3.w;
            }
        }
#pragma unroll
        for (int k = 0; k < 8; ++k) As[k][tid] = a[k];
    }
    __syncthreads();

    int tx = tid & 15;
    int ty = tid >> 4;
    float acc[8][8];
#pragma unroll
    for (int i = 0; i < 8; ++i)
#pragma unroll
        for (int j = 0; j < 8; ++j) acc[i][j] = 0.f;

#pragma unroll
    for (int k = 0; k < 8; ++k) {
        float a[8], b[8];
        float4 a0 = *(const float4*)&As[k][ty * 4];
        float4 a1 = *(const float4*)&As[k][ty * 4 + 64];
        float4 b0 = *(const float4*)&Bs[k][tx * 4];
        float4 b1 = *(const float4*)&Bs[k][tx * 4 + 64];
        a[0] = a0.x; a[1] = a0.y; a[2] = a0.z; a[3] = a0.w;
        a[4] = a1.x; a[5] = a1.y; a[6] = a1.z; a[7] = a1.w;
        b[0] = b0.x; b[1] = b0.y; b[2] = b0.z; b[3] = b0.w;
        b[4] = b1.x; b[5] = b1.y; b[6] = b1.z; b[7] = b1.w;
#pragma unroll
        for (int i = 0; i < 8; ++i)
#pragma unroll
            for (int j = 0; j < 8; ++j) acc[i][j] += a[i] * b[j];
    }

    float4 bi0 = *(const float4*)&b1[tx * 4];
    float4 bi1 = *(const float4*)&b1[tx * 4 + 64];
    float bb[8] = {bi0.x, bi0.y, bi0.z, bi0.w, bi1.x, bi1.y, bi1.z, bi1.w};
#pragma unroll
    for (int i = 0; i < 8; ++i) {
        int gm = bm + ((i < 4) ? (ty * 4 + i) : (64 + ty * 4 + i - 4));
        if (gm >= N) continue;
        ushort4 v0, v1;
        v0.x = f2bf(fmaxf(acc[i][0] + bb[0], 0.f));
        v0.y = f2bf(fmaxf(acc[i][1] + bb[1], 0.f));
        v0.z = f2bf(fmaxf(acc[i][2] + bb[2], 0.f));
        v0.w = f2bf(fmaxf(acc[i][3] + bb[3], 0.f));
        v1.x = f2bf(fmaxf(acc[i][4] + bb[4], 0.f));
        v1.y = f2bf(fmaxf(acc[i][5] + bb[5], 0.f));
        v1.z = f2bf(fmaxf(acc[i][6] + bb[6], 0.f));
        v1.w = f2bf(fmaxf(acc[i][7] + bb[7], 0.f));
        *(ushort4*)&h1[(size_t)gm * 128 + tx * 4] = v0;
        *(ushort4*)&h1[(size_t)gm * 128 + tx * 4 + 64] = v1;
    }
}

// ---------------- aggregation, bf16 in -> bf16 out, 8 feats/thread, 4-wide MLP gather ----------------

__global__ void k_agg_bf(const unsigned short* __restrict__ h, const float* __restrict__ dinv,
                         const int* __restrict__ esrc, const float* __restrict__ enorm,
                         const int* __restrict__ row_start,
                         unsigned short* __restrict__ A,
                         int N, int Mpad, int F, int osh) {
    int p = blockIdx.x * blockDim.x + threadIdx.x;
    int oct = F >> 3;
    if (p >= Mpad * oct) return;
    int n = p >> osh;
    int fo = (p & (oct - 1)) << 3;
    size_t oidx = (size_t)n * F + fo;
    if (n >= N) {
        *(uint4*)&A[oidx] = make_uint4(0, 0, 0, 0);
        return;
    }
    float dv = dinv[n];
    float dv2 = dv * dv;
    uint4 hv = *(const uint4*)&h[oidx];
    float s0 = bfu_lo(hv.x) * dv2, s1 = bfu_hi(hv.x) * dv2;
    float s2 = bfu_lo(hv.y) * dv2, s3 = bfu_hi(hv.y) * dv2;
    float s4 = bfu_lo(hv.z) * dv2, s5 = bfu_hi(hv.z) * dv2;
    float s6 = bfu_lo(hv.w) * dv2, s7 = bfu_hi(hv.w) * dv2;
    int j0 = row_start[n], j1 = row_start[n + 1];
    for (int b = j0; b < j1; b += 4) {
        int i1 = (b + 1 < j1) ? b + 1 : b;
        int i2 = (b + 2 < j1) ? b + 2 : b;
        int i3 = (b + 3 < j1) ? b + 3 : b;
        float w0 = enorm[b];
        float w1 = (b + 1 < j1) ? enorm[i1] : 0.f;
        float w2 = (b + 2 < j1) ? enorm[i2] : 0.f;
        float w3 = (b + 3 < j1) ? enorm[i3] : 0.f;
        int e0 = esrc[b], e1 = esrc[i1], e2 = esrc[i2], e3 = esrc[i3];
        uint4 r0 = *(const uint4*)&h[(size_t)e0 * F + fo];
        uint4 r1 = *(const uint4*)&h[(size_t)e1 * F + fo];
        uint4 r2 = *(const uint4*)&h[(size_t)e2 * F + fo];
        uint4 r3 = *(const uint4*)&h[(size_t)e3 * F + fo];
        s0 += w0 * bfu_lo(r0.x) + w1 * bfu_lo(r1.x) + w2 * bfu_lo(r2.x) + w3 * bfu_lo(r3.x);
        s1 += w0 * bfu_hi(r0.x) + w1 * bfu_hi(r1.x) + w2 * bfu_hi(r2.x) + w3 * bfu_hi(r3.x);
        s2 += w0 * bfu_lo(r0.y) + w1 * bfu_lo(r1.y) + w2 * bfu_lo(r2.y) + w3 * bfu_lo(r3.y);
        s3 += w0 * bfu_hi(r0.y) + w1 * bfu_hi(r1.y) + w2 * bfu_hi(r2.y) + w3 * bfu_hi(r3.y);
        s4 += w0 * bfu_lo(r0.z) + w1 * bfu_lo(r1.z) + w2 * bfu_lo(r2.z) + w3 * bfu_lo(r3.z);
        s5 += w0 * bfu_hi(r0.z) + w1 * bfu_hi(r1.z) + w2 * bfu_hi(r2.z) + w3 * bfu_hi(r3.z);
        s6 += w0 * bfu_lo(r0.w) + w1 * bfu_lo(r1.w) + w2 * bfu_lo(r2.w) + w3 * bfu_lo(r3.w);
        s7 += w0 * bfu_hi(r0.w) + w1 * bfu_hi(r1.w) + w2 * bfu_hi(r2.w) + w3 * bfu_hi(r3.w);
    }
    uint4 o;
    o.x = (unsigned int)f2bf(s0) | ((unsigned int)f2bf(s1) << 16);
    o.y = (unsigned int)f2bf(s2) | ((unsigned int)f2bf(s3) << 16);
    o.z = (unsigned int)f2bf(s4) | ((unsigned int)f2bf(s5) << 16);
    o.w = (unsigned int)f2bf(s6) | ((unsigned int)f2bf(s7) << 16);
    *(uint4*)&A[oidx] = o;
}

// ---------------- bf16 MFMA GEMM, async LDS staging, XCD-aware swizzle ----------------
// EPI=0: C = relu(A@W+bias) bf16. EPI=1: fused FC + pool: per-graph atomics into
// gsum, last block computes mean+sigmoid -> out.

template <int EPI>
__global__ __launch_bounds__(256, 4) void k_gemm_async(
    const unsigned short* __restrict__ A, const unsigned short* __restrict__ B,
    const float* __restrict__ bias, unsigned short* __restrict__ C,
    const float* __restrict__ Wfc, const int* __restrict__ batch,
    float* __restrict__ gsum, int* __restrict__ done,
    const float* __restrict__ bfc, float* __restrict__ outp,
    int M, int Mpad, int K, int Fout, int nbsh, int G, int nblocks) {
    __shared__ __align__(16) unsigned short smem[8192];  // 16 KB
    __shared__ int lastFlag;

    int tid = threadIdx.x, wave = tid >> 6, lane = tid & 63;
    int quad = lane >> 4, r = lane & 15;

    // XCD swizzle: all bn-blocks of one bm-group land on the same XCD
    int P = blockIdx.x;
    int r8 = P & 7;
    int q = P >> 3;
    int bnIdx = q & ((1 << nbsh) - 1);
    int g = ((q >> nbsh) << 3) + r8;
    int bm = g * 128, bn = bnIdx * 128;
    int wm = (wave & 1) * 64, wn = (wave >> 1) * 64;

    const unsigned short* gsrc[2] = {A, B};
    const int rb[2] = {bm, bn};

    floatx4 acc[4][4] = {};

    for (int k0 = 0; k0 < K; k0 += 32) {
#pragma unroll
        for (int t = 0; t < 2; ++t) {
#pragma unroll
            for (int i = 0; i < 2; ++i) {
                int qc = wave * 2 + i;
                int idx = qc * 64 + lane;
                int row = idx >> 2, kofs = (idx & 3) << 3;
                const unsigned short* gptr = gsrc[t] + ((size_t)(rb[t] + row) * K + k0 + kofs);
                unsigned short* l = &smem[t * 4096 + qc * 512];
                __builtin_amdgcn_global_load_lds(
                    (const __attribute__((address_space(1))) void*)gptr,
                    (__attribute__((address_space(3))) void*)l, 16, 0, 0);
            }
        }
        __syncthreads();

        short8 ah[4];
#pragma unroll
        for (int mt = 0; mt < 4; ++mt) {
            int m = wm + mt * 16 + r;
            ah[mt] = *(const short8*)&smem[m * 32 + quad * 8];
        }
#pragma unroll
        for (int nt = 0; nt < 4; ++nt) {
            int n = wn + nt * 16 + r;
            short8 bh = *(const short8*)&smem[4096 + n * 32 + quad * 8];
#pragma unroll
            for (int mt = 0; mt < 4; ++mt)
                acc[mt][nt] = __builtin_amdgcn_mfma_f32_16x16x32_bf16(ah[mt], bh, acc[mt][nt], 0, 0, 0);
        }
        __syncthreads();
    }

    float bv[4];
#pragma unroll
    for (int nt = 0; nt < 4; ++nt) bv[nt] = bias[bn + wn + nt * 16 + r];

    if (EPI == 0) {
        float* eps = (float*)&smem[0] + wave * 1024;
#pragma unroll
        for (int mt = 0; mt < 4; ++mt) {
#pragma unroll
            for (int nt = 0; nt < 4; ++nt)
#pragma unroll
                for (int reg = 0; reg < 4; ++reg)
                    eps[(quad * 4 + reg) * 64 + nt * 16 + r] =
                        fmaxf(acc[mt][nt][reg] + bv[nt], 0.f);
#pragma unroll
            for (int i = 0; i < 4; ++i) {
                int fl = i * 64 + lane;
                int ri = fl >> 4, c4 = fl & 15;
                float4 v = *(const float4*)&eps[ri * 64 + c4 * 4];
                int gm = bm + wm + mt * 16 + ri;
                if (gm < M)
                    *(ushort4*)&C[(size_t)gm * Fout + bn + wn + c4 * 4] =
                        make_ushort4(f2bf(v.x), f2bf(v.y), f2bf(v.z), f2bf(v.w));
            }
        }
    } else {
        float* rowsum = (float*)&smem[0];        // 128 floats
        int* gsh = (int*)&smem[0] + 128;         // 128 ints (graph id per row)
        if (tid < 128) rowsum[tid] = 0.f;
        __syncthreads();
        float wf[4];
#pragma unroll
        for (int nt = 0; nt < 4; ++nt) wf[nt] = Wfc[bn + wn + nt * 16 + r];
#pragma unroll
        for (int mt = 0; mt < 4; ++mt)
#pragma unroll
            for (int reg = 0; reg < 4; ++reg) {
                float v = 0.f;
#pragma unroll
                for (int nt = 0; nt < 4; ++nt)
                    v += fmaxf(acc[mt][nt][reg] + bv[nt], 0.f) * wf[nt];
                v += __shfl_xor(v, 1);
                v += __shfl_xor(v, 2);
                v += __shfl_xor(v, 4);
                v += __shfl_xor(v, 8);
                if (r == 0) atomicAdd(&rowsum[wm + mt * 16 + quad * 4 + reg], v);
            }
        if (tid < 128) {
            int gm = bm + tid;
            gsh[tid] = (gm < M) ? batch[gm] : -1;
        }
        __syncthreads();
        // run leaders (batch sorted -> few runs/block) do one atomic per run
        if (tid < 128) {
            int gg = gsh[tid];
            if (gg >= 0 && (tid == 0 || gsh[tid - 1] != gg)) {
                float s = 0.f;
                int t2 = tid;
                while (t2 < 128 && gsh[t2] == gg) { s += rowsum[t2]; ++t2; }
                atomicAdd(&gsum[gg], s);
            }
        }
        __threadfence();
        __syncthreads();
        if (tid == 0) lastFlag = (atomicAdd(done, 1) == nblocks - 1) ? 1 : 0;
        __syncthreads();
        if (lastFlag) {
            for (int gi = tid; gi < G; gi += 256) {
                int lo = 0, hi = M;
                while (lo < hi) { int m = (lo + hi) >> 1; if (batch[m] < gi) lo = m + 1; else hi = m; }
                int start = lo;
                hi = M;
                while (lo < hi) { int m = (lo + hi) >> 1; if (batch[m] < gi + 1) lo = m + 1; else hi = m; }
                float c = (float)(lo - start);
                if (c < 1.f) c = 1.f;
                float s = atomicAdd(&gsum[gi], 0.f);  // device-coherent read
                float z = s / c + bfc[0];
                outp[gi] = 1.f / (1.f + expf(-z));
            }
        }
    }
}

// ---------------- launcher ----------------

static inline int cdiv(int a, int b) { return (a + b - 1) / b; }

extern "C" void kernel_launch(void* const* d_in, const int* in_sizes, int n_in,
                              void* d_out, int out_size, void* d_ws, size_t ws_size,
                              hipStream_t stream) {
    const float* x   = (const float*)d_in[0];
    const int*   ei  = (const int*)d_in[1];
    const float* ew  = (const float*)d_in[2];
    const int*   bat = (const int*)d_in[3];
    const float* W1  = (const float*)d_in[4];
    const float* b1  = (const float*)d_in[5];
    const float* W2  = (const float*)d_in[6];
    const float* b2  = (const float*)d_in[7];
    const float* W3  = (const float*)d_in[8];
    const float* b3  = (const float*)d_in[9];
    const float* Wfc = (const float*)d_in[10];
    const float* bfc = (const float*)d_in[11];
    float* out = (float*)d_out;

    const int N  = in_sizes[3];
    const int E  = in_sizes[2];
    const int H1 = in_sizes[5];       // 128
    const int H2 = in_sizes[7];       // 256
    const int H3 = in_sizes[9];       // 512
    const int G  = out_size;          // 256
    const int Mpad = cdiv(N, 1024) * 1024;  // /128 divisible by 8 (XCD swizzle)
    const int Npad4 = (N + 4) & ~3;

    const int* srcv = ei;
    const int* dstv = ei + E;

    char* p = (char*)d_ws;
    float* dinv      = (float*)p; p += (size_t)N * 4;   // deg, then rsqrt in place
    int*   cnt       = (int*)p;   p += (size_t)N * 4;
    int*   cursor    = (int*)p;   p += (size_t)N * 4;
    int*   bsum      = (int*)p;   p += 256 * 4;
    int*   row_start = (int*)p;   p += (size_t)Npad4 * 4;
    int*   esrc      = (int*)p;   p += (size_t)E * 4;
    float* enorm     = (float*)p; p += (size_t)E * 4;
    float* gsum      = (float*)p; p += (size_t)G * 4;
    int*   done      = (int*)p;   p += 16;
    unsigned short* WT2 = (unsigned short*)p; p += (size_t)H1 * H2 * 2;
    unsigned short* WT3 = (unsigned short*)p; p += (size_t)H2 * H3 * 2;
    unsigned short* Abf = (unsigned short*)p; p += (size_t)Mpad * H2 * 2;
    unsigned short* h1  = (unsigned short*)p; p += (size_t)Mpad * H1 * 2;
    unsigned short* h2  = (unsigned short*)p; p += (size_t)Mpad * H2 * 2;

    // ---- precompute (5 launches, no grid sync)
    int initTot = H1 * H2 + H2 * H3;
    if (initTot < N) initTot = N;
    k_init_wt<<<cdiv(initTot, 256), 256, 0, stream>>>(dinv, cnt, cursor, N,
                                                      W2, WT2, H1, H2, W3, WT3, H2, H3,
                                                      gsum, done, G);
    k_hist_deg<<<cdiv(E, 256), 256, 0, stream>>>(dstv, ew, dinv, cnt, E);
    int nb = cdiv(N, 1024);
    k_dinv_scana<<<nb, 256, 0, stream>>>(dinv, cnt, bsum, N);
    k_scan_c<<<nb, 256, 0, stream>>>(cnt, bsum, row_start, N, nb);
    k_scatter_norm<<<cdiv(E, 256), 256, 0, stream>>>(srcv, dstv, ew, dinv, row_start,
                                                     cursor, esrc, enorm, E);

    // ---- layer 1: fused agg + fp32 GEMM -> h1 bf16 [N,128]
    k_l1_gemm<<<cdiv(N, 128), 256, 0, stream>>>(x, dinv, esrc, enorm, row_start, W1, b1, h1, N);

    // ---- layer 2: agg(h1 bf16) -> Abf -> MFMA GEMM -> h2 bf16 [N,256]
    k_agg_bf<<<cdiv(Mpad * (H1 / 8), 256), 256, 0, stream>>>(
        h1, dinv, esrc, enorm, row_start, Abf, N, Mpad, H1, __builtin_ctz(H1) - 3);
    k_gemm_async<0><<<(Mpad / 128) * (H2 / 128), 256, 0, stream>>>(
        Abf, WT2, b2, h2, nullptr, nullptr, nullptr, nullptr, nullptr, nullptr,
        N, Mpad, H1, H2, __builtin_ctz(H2 / 128), G, 0);

    // ---- layer 3: agg(h2 bf16) -> Abf -> MFMA GEMM + fused FC + pool -> out
    k_agg_bf<<<cdiv(Mpad * (H2 / 8), 256), 256, 0, stream>>>(
        h2, dinv, esrc, enorm, row_start, Abf, N, Mpad, H2, __builtin_ctz(H2) - 3);
    int nblocks3 = (Mpad / 128) * (H3 / 128);
    k_gemm_async<1><<<nblocks3, 256, 0, stream>>>(
        Abf, WT3, b3, nullptr, Wfc, bat, gsum, done, bfc, out,
        N, Mpad, H2, H3, __builtin_ctz(H3 / 128), G, nblocks3);
}

// Round 12
// 217.910 us; speedup vs baseline: 1.3855x; 1.3855x over previous
//
#include <hip/hip_runtime.h>
#include <math.h>

typedef __attribute__((ext_vector_type(8))) short short8;
typedef __attribute__((ext_vector_type(4))) float floatx4;

// ---------------- bf16 helpers ----------------

__device__ __forceinline__ unsigned short f2bf(float f) {
    unsigned int u = __float_as_uint(f);
    unsigned int r = (u + 0x7fffu + ((u >> 16) & 1u)) >> 16;  // RNE
    return (unsigned short)r;
}
__device__ __forceinline__ float bfu_lo(unsigned int u) {
    return __uint_as_float(u << 16);
}
__device__ __forceinline__ float bfu_hi(unsigned int u) {
    return __uint_as_float(u & 0xffff0000u);
}

// ---------------- precompute ----------------

// init deg/cnt/cursor + both weight transposes (one launch)
__global__ void k_init_wt(float* __restrict__ deg, int* __restrict__ cnt,
                          int* __restrict__ cursor, int N,
                          const float* __restrict__ W2, unsigned short* __restrict__ WT2,
                          int K2, int F2,
                          const float* __restrict__ W3, unsigned short* __restrict__ WT3,
                          int K3, int F3) {
    int i = blockIdx.x * blockDim.x + threadIdx.x;
    if (i < N) { deg[i] = 1.0f; cnt[i] = 0; cursor[i] = 0; }
    int n2 = K2 * F2;
    if (i < n2) {
        int k = i / F2, n = i % F2;
        WT2[(size_t)n * K2 + k] = f2bf(W2[i]);
    } else {
        int j = i - n2;
        if (j < K3 * F3) {
            int k = j / F3, n = j % F3;
            WT3[(size_t)n * K3 + k] = f2bf(W3[j]);
        }
    }
}

__global__ void k_hist_deg(const int* __restrict__ dst, const float* __restrict__ ew,
                           float* __restrict__ deg, int* __restrict__ cnt, int E) {
    int e = blockIdx.x * blockDim.x + threadIdx.x;
    if (e < E) {
        int d = dst[e];
        atomicAdd(&deg[d], ew[e]);
        atomicAdd(&cnt[d], 1);
    }
}

// fused: deg -> rsqrt in place (dinv) AND per-block cnt sums for the scan
__global__ __launch_bounds__(256) void k_dinv_scana(float* __restrict__ deg,
                                                    const int* __restrict__ cnt,
                                                    int* __restrict__ bsum, int N) {
    int b = blockIdx.x, t = threadIdx.x;
    int base = b * 1024 + t * 4;
    int s = 0;
#pragma unroll
    for (int j = 0; j < 4; ++j) {
        int i = base + j;
        if (i < N) { deg[i] = rsqrtf(deg[i]); s += cnt[i]; }
    }
    __shared__ int sh[256];
    sh[t] = s; __syncthreads();
    for (int st = 128; st > 0; st >>= 1) { if (t < st) sh[t] += sh[t + st]; __syncthreads(); }
    if (t == 0) bsum[b] = sh[0];
}

// scan_c with inlined cross-block offset
__global__ __launch_bounds__(256) void k_scan_c(const int* __restrict__ cnt,
                                                const int* __restrict__ bsum,
                                                int* __restrict__ row_start, int N, int nb) {
    int b = blockIdx.x, t = threadIdx.x;
    __shared__ int sh[256];
    __shared__ int boffs;

    if (t < 64) {
        int s = 0;
        for (int i = t; i < b; i += 64) s += bsum[i];
#pragma unroll
        for (int off = 32; off > 0; off >>= 1) s += __shfl_down(s, off);
        if (t == 0) boffs = s;
    }
    __syncthreads();

    int base = b * 1024 + t * 4;
    int v[4]; int s = 0;
#pragma unroll
    for (int j = 0; j < 4; ++j) { int i = base + j; v[j] = (i < N) ? cnt[i] : 0; s += v[j]; }
    sh[t] = s; __syncthreads();
    for (int off = 1; off < 256; off <<= 1) {
        int x = (t >= off) ? sh[t - off] : 0;
        __syncthreads();
        sh[t] += x;
        __syncthreads();
    }
    int excl = sh[t] - s + boffs;
#pragma unroll
    for (int j = 0; j < 4; ++j) {
        int i = base + j;
        if (i < N) row_start[i] = excl;
        excl += v[j];
        if (i == N - 1) row_start[N] = excl;
    }
}

// fused: CSR scatter + norm computation
__global__ void k_scatter_norm(const int* __restrict__ src, const int* __restrict__ dst,
                               const float* __restrict__ ew, const float* __restrict__ dinv,
                               const int* __restrict__ row_start, int* __restrict__ cursor,
                               int* __restrict__ esrc, float* __restrict__ enorm, int E) {
    int e = blockIdx.x * blockDim.x + threadIdx.x;
    if (e >= E) return;
    int d = dst[e], s = src[e];
    int pos = row_start[d] + atomicAdd(&cursor[d], 1);
    esrc[pos] = s;
    enorm[pos] = dinv[s] * ew[e] * dinv[d];
}

// ---------------- layer 1: fused agg(x)[N,8] + fp32 GEMM(K=8) -> relu -> h1 bf16 ----------------

__global__ __launch_bounds__(256) void k_l1_gemm(
    const float* __restrict__ x, const float* __restrict__ dinv,
    const int* __restrict__ esrc, const float* __restrict__ enorm,
    const int* __restrict__ row_start, const float* __restrict__ W1,
    const float* __restrict__ b1, unsigned short* __restrict__ h1, int N) {
    __shared__ float As[8][132];
    __shared__ float Bs[8][128];

    int tid = threadIdx.x;
    int bm = blockIdx.x * 128;

#pragma unroll
    for (int i = tid; i < 1024; i += 256) Bs[i >> 7][i & 127] = W1[i];

    if (tid < 128) {
        int n = bm + tid;
        float a[8] = {0, 0, 0, 0, 0, 0, 0, 0};
        if (n < N) {
            float dv = dinv[n];
            float dv2 = dv * dv;
            float4 v0 = *(const float4*)&x[(size_t)n * 8];
            float4 v1 = *(const float4*)&x[(size_t)n * 8 + 4];
            a[0] = v0.x * dv2; a[1] = v0.y * dv2; a[2] = v0.z * dv2; a[3] = v0.w * dv2;
            a[4] = v1.x * dv2; a[5] = v1.y * dv2; a[6] = v1.z * dv2; a[7] = v1.w * dv2;
            int j0 = row_start[n], j1 = row_start[n + 1];
            // 4-wide MLP gather: 4 independent row loads in flight
            for (int b = j0; b < j1; b += 4) {
                int i1 = (b + 1 < j1) ? b + 1 : b;
                int i2 = (b + 2 < j1) ? b + 2 : b;
                int i3 = (b + 3 < j1) ? b + 3 : b;
                float w0 = enorm[b];
                float w1 = (b + 1 < j1) ? enorm[i1] : 0.f;
                float w2 = (b + 2 < j1) ? enorm[i2] : 0.f;
                float w3 = (b + 3 < j1) ? enorm[i3] : 0.f;
                int s0 = esrc[b], s1 = esrc[i1], s2 = esrc[i2], s3 = esrc[i3];
                float4 p0 = *(const float4*)&x[(size_t)s0 * 8];
                float4 q0 = *(const float4*)&x[(size_t)s0 * 8 + 4];
                float4 p1 = *(const float4*)&x[(size_t)s1 * 8];
                float4 q1 = *(const float4*)&x[(size_t)s1 * 8 + 4];
                float4 p2 = *(const float4*)&x[(size_t)s2 * 8];
                float4 q2 = *(const float4*)&x[(size_t)s2 * 8 + 4];
                float4 p3 = *(const float4*)&x[(size_t)s3 * 8];
                float4 q3 = *(const float4*)&x[(size_t)s3 * 8 + 4];
                a[0] += w0 * p0.x + w1 * p1.x + w2 * p2.x + w3 * p3.x;
                a[1] += w0 * p0.y + w1 * p1.y + w2 * p2.y + w3 * p3.y;
                a[2] += w0 * p0.z + w1 * p1.z + w2 * p2.z + w3 * p3.z;
                a[3] += w0 * p0.w + w1 * p1.w + w2 * p2.w + w3 * p3.w;
                a[4] += w0 * q0.x + w1 * q1.x + w2 * q2.x + w3 * q3.x;
                a[5] += w0 * q0.y + w1 * q1.y + w2 * q2.y + w3 * q3.y;
                a[6] += w0 * q0.z + w1 * q1.z + w2 * q2.z + w3 * q3.z;
                a[7] += w0 * q0.w + w1 * q1.w + w2 * q2.w + w3 * q3.w;
            }
        }
#pragma unroll
        for (int k = 0; k < 8; ++k) As[k][tid] = a[k];
    }
    __syncthreads();

    int tx = tid & 15;
    int ty = tid >> 4;
    float acc[8][8];
#pragma unroll
    for (int i = 0; i < 8; ++i)
#pragma unroll
        for (int j = 0; j < 8; ++j) acc[i][j] = 0.f;

#pragma unroll
    for (int k = 0; k < 8; ++k) {
        float a[8], b[8];
        float4 a0 = *(const float4*)&As[k][ty * 4];
        float4 a1 = *(const float4*)&As[k][ty * 4 + 64];
        float4 b0 = *(const float4*)&Bs[k][tx * 4];
        float4 b1 = *(const float4*)&Bs[k][tx * 4 + 64];
        a[0] = a0.x; a[1] = a0.y; a[2] = a0.z; a[3] = a0.w;
        a[4] = a1.x; a[5] = a1.y; a[6] = a1.z; a[7] = a1.w;
        b[0] = b0.x; b[1] = b0.y; b[2] = b0.z; b[3] = b0.w;
        b[4] = b1.x; b[5] = b1.y; b[6] = b1.z; b[7] = b1.w;
#pragma unroll
        for (int i = 0; i < 8; ++i)
#pragma unroll
            for (int j = 0; j < 8; ++j) acc[i][j] += a[i] * b[j];
    }

    float4 bi0 = *(const float4*)&b1[tx * 4];
    float4 bi1 = *(const float4*)&b1[tx * 4 + 64];
    float bb[8] = {bi0.x, bi0.y, bi0.z, bi0.w, bi1.x, bi1.y, bi1.z, bi1.w};
#pragma unroll
    for (int i = 0; i < 8; ++i) {
        int gm = bm + ((i < 4) ? (ty * 4 + i) : (64 + ty * 4 + i - 4));
        if (gm >= N) continue;
        ushort4 v0, v1;
        v0.x = f2bf(fmaxf(acc[i][0] + bb[0], 0.f));
        v0.y = f2bf(fmaxf(acc[i][1] + bb[1], 0.f));
        v0.z = f2bf(fmaxf(acc[i][2] + bb[2], 0.f));
        v0.w = f2bf(fmaxf(acc[i][3] + bb[3], 0.f));
        v1.x = f2bf(fmaxf(acc[i][4] + bb[4], 0.f));
        v1.y = f2bf(fmaxf(acc[i][5] + bb[5], 0.f));
        v1.z = f2bf(fmaxf(acc[i][6] + bb[6], 0.f));
        v1.w = f2bf(fmaxf(acc[i][7] + bb[7], 0.f));
        *(ushort4*)&h1[(size_t)gm * 128 + tx * 4] = v0;
        *(ushort4*)&h1[(size_t)gm * 128 + tx * 4 + 64] = v1;
    }
}

// ---------------- aggregation, bf16 in -> bf16 out, 8 feats/thread, 4-wide MLP gather ----------------

__global__ void k_agg_bf(const unsigned short* __restrict__ h, const float* __restrict__ dinv,
                         const int* __restrict__ esrc, const float* __restrict__ enorm,
                         const int* __restrict__ row_start,
                         unsigned short* __restrict__ A,
                         int N, int Mpad, int F, int osh) {
    int p = blockIdx.x * blockDim.x + threadIdx.x;
    int oct = F >> 3;
    if (p >= Mpad * oct) return;
    int n = p >> osh;
    int fo = (p & (oct - 1)) << 3;
    size_t oidx = (size_t)n * F + fo;
    if (n >= N) {
        *(uint4*)&A[oidx] = make_uint4(0, 0, 0, 0);
        return;
    }
    float dv = dinv[n];
    float dv2 = dv * dv;
    uint4 hv = *(const uint4*)&h[oidx];
    float s0 = bfu_lo(hv.x) * dv2, s1 = bfu_hi(hv.x) * dv2;
    float s2 = bfu_lo(hv.y) * dv2, s3 = bfu_hi(hv.y) * dv2;
    float s4 = bfu_lo(hv.z) * dv2, s5 = bfu_hi(hv.z) * dv2;
    float s6 = bfu_lo(hv.w) * dv2, s7 = bfu_hi(hv.w) * dv2;
    int j0 = row_start[n], j1 = row_start[n + 1];
    for (int b = j0; b < j1; b += 4) {
        int i1 = (b + 1 < j1) ? b + 1 : b;
        int i2 = (b + 2 < j1) ? b + 2 : b;
        int i3 = (b + 3 < j1) ? b + 3 : b;
        float w0 = enorm[b];
        float w1 = (b + 1 < j1) ? enorm[i1] : 0.f;
        float w2 = (b + 2 < j1) ? enorm[i2] : 0.f;
        float w3 = (b + 3 < j1) ? enorm[i3] : 0.f;
        int e0 = esrc[b], e1 = esrc[i1], e2 = esrc[i2], e3 = esrc[i3];
        uint4 r0 = *(const uint4*)&h[(size_t)e0 * F + fo];
        uint4 r1 = *(const uint4*)&h[(size_t)e1 * F + fo];
        uint4 r2 = *(const uint4*)&h[(size_t)e2 * F + fo];
        uint4 r3 = *(const uint4*)&h[(size_t)e3 * F + fo];
        s0 += w0 * bfu_lo(r0.x) + w1 * bfu_lo(r1.x) + w2 * bfu_lo(r2.x) + w3 * bfu_lo(r3.x);
        s1 += w0 * bfu_hi(r0.x) + w1 * bfu_hi(r1.x) + w2 * bfu_hi(r2.x) + w3 * bfu_hi(r3.x);
        s2 += w0 * bfu_lo(r0.y) + w1 * bfu_lo(r1.y) + w2 * bfu_lo(r2.y) + w3 * bfu_lo(r3.y);
        s3 += w0 * bfu_hi(r0.y) + w1 * bfu_hi(r1.y) + w2 * bfu_hi(r2.y) + w3 * bfu_hi(r3.y);
        s4 += w0 * bfu_lo(r0.z) + w1 * bfu_lo(r1.z) + w2 * bfu_lo(r2.z) + w3 * bfu_lo(r3.z);
        s5 += w0 * bfu_hi(r0.z) + w1 * bfu_hi(r1.z) + w2 * bfu_hi(r2.z) + w3 * bfu_hi(r3.z);
        s6 += w0 * bfu_lo(r0.w) + w1 * bfu_lo(r1.w) + w2 * bfu_lo(r2.w) + w3 * bfu_lo(r3.w);
        s7 += w0 * bfu_hi(r0.w) + w1 * bfu_hi(r1.w) + w2 * bfu_hi(r2.w) + w3 * bfu_hi(r3.w);
    }
    uint4 o;
    o.x = (unsigned int)f2bf(s0) | ((unsigned int)f2bf(s1) << 16);
    o.y = (unsigned int)f2bf(s2) | ((unsigned int)f2bf(s3) << 16);
    o.z = (unsigned int)f2bf(s4) | ((unsigned int)f2bf(s5) << 16);
    o.w = (unsigned int)f2bf(s6) | ((unsigned int)f2bf(s7) << 16);
    *(uint4*)&A[oidx] = o;
}

// ---------------- bf16 MFMA GEMM, async LDS staging, XCD-aware swizzle ----------------
// EPI=0: C = relu(A@W+bias) bf16. EPI=1: fused FC dot -> part[bnIdx*Mpad+row].

template <int EPI>
__global__ __launch_bounds__(256, 4) void k_gemm_async(
    const unsigned short* __restrict__ A, const unsigned short* __restrict__ B,
    const float* __restrict__ bias, unsigned short* __restrict__ C,
    const float* __restrict__ Wfc, float* __restrict__ part,
    int M, int Mpad, int K, int Fout, int nbsh) {
    __shared__ __align__(16) unsigned short smem[8192];  // 16 KB

    int tid = threadIdx.x, wave = tid >> 6, lane = tid & 63;
    int quad = lane >> 4, r = lane & 15;

    // XCD swizzle: all bn-blocks of one bm-group land on the same XCD
    int P = blockIdx.x;
    int r8 = P & 7;
    int q = P >> 3;
    int bnIdx = q & ((1 << nbsh) - 1);
    int g = ((q >> nbsh) << 3) + r8;
    int bm = g * 128, bn = bnIdx * 128;
    int wm = (wave & 1) * 64, wn = (wave >> 1) * 64;

    const unsigned short* gsrc[2] = {A, B};
    const int rb[2] = {bm, bn};

    floatx4 acc[4][4] = {};

    for (int k0 = 0; k0 < K; k0 += 32) {
#pragma unroll
        for (int t = 0; t < 2; ++t) {
#pragma unroll
            for (int i = 0; i < 2; ++i) {
                int qc = wave * 2 + i;
                int idx = qc * 64 + lane;
                int row = idx >> 2, kofs = (idx & 3) << 3;
                const unsigned short* gptr = gsrc[t] + ((size_t)(rb[t] + row) * K + k0 + kofs);
                unsigned short* l = &smem[t * 4096 + qc * 512];
                __builtin_amdgcn_global_load_lds(
                    (const __attribute__((address_space(1))) void*)gptr,
                    (__attribute__((address_space(3))) void*)l, 16, 0, 0);
            }
        }
        __syncthreads();

        short8 ah[4];
#pragma unroll
        for (int mt = 0; mt < 4; ++mt) {
            int m = wm + mt * 16 + r;
            ah[mt] = *(const short8*)&smem[m * 32 + quad * 8];
        }
#pragma unroll
        for (int nt = 0; nt < 4; ++nt) {
            int n = wn + nt * 16 + r;
            short8 bh = *(const short8*)&smem[4096 + n * 32 + quad * 8];
#pragma unroll
            for (int mt = 0; mt < 4; ++mt)
                acc[mt][nt] = __builtin_amdgcn_mfma_f32_16x16x32_bf16(ah[mt], bh, acc[mt][nt], 0, 0, 0);
        }
        __syncthreads();
    }

    float bv[4];
#pragma unroll
    for (int nt = 0; nt < 4; ++nt) bv[nt] = bias[bn + wn + nt * 16 + r];

    if (EPI == 0) {
        float* eps = (float*)&smem[0] + wave * 1024;
#pragma unroll
        for (int mt = 0; mt < 4; ++mt) {
#pragma unroll
            for (int nt = 0; nt < 4; ++nt)
#pragma unroll
                for (int reg = 0; reg < 4; ++reg)
                    eps[(quad * 4 + reg) * 64 + nt * 16 + r] =
                        fmaxf(acc[mt][nt][reg] + bv[nt], 0.f);
#pragma unroll
            for (int i = 0; i < 4; ++i) {
                int fl = i * 64 + lane;
                int ri = fl >> 4, c4 = fl & 15;
                float4 v = *(const float4*)&eps[ri * 64 + c4 * 4];
                int gm = bm + wm + mt * 16 + ri;
                if (gm < M)
                    *(ushort4*)&C[(size_t)gm * Fout + bn + wn + c4 * 4] =
                        make_ushort4(f2bf(v.x), f2bf(v.y), f2bf(v.z), f2bf(v.w));
            }
        }
    } else {
        float* rowsum = (float*)&smem[0];
        if (tid < 128) rowsum[tid] = 0.f;
        __syncthreads();
        float wf[4];
#pragma unroll
        for (int nt = 0; nt < 4; ++nt) wf[nt] = Wfc[bn + wn + nt * 16 + r];
#pragma unroll
        for (int mt = 0; mt < 4; ++mt)
#pragma unroll
            for (int reg = 0; reg < 4; ++reg) {
                float v = 0.f;
#pragma unroll
                for (int nt = 0; nt < 4; ++nt)
                    v += fmaxf(acc[mt][nt][reg] + bv[nt], 0.f) * wf[nt];
                v += __shfl_xor(v, 1);
                v += __shfl_xor(v, 2);
                v += __shfl_xor(v, 4);
                v += __shfl_xor(v, 8);
                if (r == 0) atomicAdd(&rowsum[wm + mt * 16 + quad * 4 + reg], v);
            }
        __syncthreads();
        if (tid < 128) part[(size_t)bnIdx * Mpad + bm + tid] = rowsum[tid];
    }
}

// ---------------- pool: sum partials; segment mean + sigmoid ----------------

__global__ __launch_bounds__(256) void k_pool2(const float* __restrict__ part,
                                               const int* __restrict__ batch,
                                               const float* __restrict__ bfc,
                                               float* __restrict__ out,
                                               int N, int Mpad, int nchunks, int G) {
    int g = (int)((blockIdx.x * blockDim.x + threadIdx.x) >> 6);
    int lane = threadIdx.x & 63;
    if (g >= G) return;
    int lo = 0, hi = N;
    while (lo < hi) { int m = (lo + hi) >> 1; if (batch[m] < g) lo = m + 1; else hi = m; }
    int start = lo;
    hi = N;
    while (lo < hi) { int m = (lo + hi) >> 1; if (batch[m] < g + 1) lo = m + 1; else hi = m; }
    int end = lo;
    float s = 0.f;
    for (int i = start + lane; i < end; i += 64) {
        float t = 0.f;
        for (int c = 0; c < nchunks; ++c) t += part[(size_t)c * Mpad + i];
        s += t;
    }
#pragma unroll
    for (int off = 32; off > 0; off >>= 1) s += __shfl_down(s, off);
    if (lane == 0) {
        float c = (float)(end - start);
        if (c < 1.f) c = 1.f;
        float z = s / c + bfc[0];
        out[g] = 1.f / (1.f + expf(-z));
    }
}

// ---------------- launcher ----------------

static inline int cdiv(int a, int b) { return (a + b - 1) / b; }

extern "C" void kernel_launch(void* const* d_in, const int* in_sizes, int n_in,
                              void* d_out, int out_size, void* d_ws, size_t ws_size,
                              hipStream_t stream) {
    const float* x   = (const float*)d_in[0];
    const int*   ei  = (const int*)d_in[1];
    const float* ew  = (const float*)d_in[2];
    const int*   bat = (const int*)d_in[3];
    const float* W1  = (const float*)d_in[4];
    const float* b1  = (const float*)d_in[5];
    const float* W2  = (const float*)d_in[6];
    const float* b2  = (const float*)d_in[7];
    const float* W3  = (const float*)d_in[8];
    const float* b3  = (const float*)d_in[9];
    const float* Wfc = (const float*)d_in[10];
    const float* bfc = (const float*)d_in[11];
    float* out = (float*)d_out;

    const int N  = in_sizes[3];
    const int E  = in_sizes[2];
    const int H1 = in_sizes[5];       // 128
    const int H2 = in_sizes[7];       // 256
    const int H3 = in_sizes[9];       // 512
    const int G  = out_size;          // 256
    const int Mpad = cdiv(N, 1024) * 1024;  // /128 divisible by 8 (XCD swizzle)
    const int Npad4 = (N + 4) & ~3;

    const int* srcv = ei;
    const int* dstv = ei + E;

    char* p = (char*)d_ws;
    float* dinv      = (float*)p; p += (size_t)N * 4;   // deg, then rsqrt in place
    int*   cnt       = (int*)p;   p += (size_t)N * 4;
    int*   cursor    = (int*)p;   p += (size_t)N * 4;
    int*   bsum      = (int*)p;   p += 256 * 4;
    int*   row_start = (int*)p;   p += (size_t)Npad4 * 4;
    int*   esrc      = (int*)p;   p += (size_t)E * 4;
    float* enorm     = (float*)p; p += (size_t)E * 4;
    float* part      = (float*)p; p += (size_t)(H3 / 128) * Mpad * 4;
    unsigned short* WT2 = (unsigned short*)p; p += (size_t)H1 * H2 * 2;
    unsigned short* WT3 = (unsigned short*)p; p += (size_t)H2 * H3 * 2;
    unsigned short* Abf = (unsigned short*)p; p += (size_t)Mpad * H2 * 2;
    unsigned short* h1  = (unsigned short*)p; p += (size_t)Mpad * H1 * 2;
    unsigned short* h2  = (unsigned short*)p; p += (size_t)Mpad * H2 * 2;

    // ---- precompute (5 launches, no grid sync, no device fences)
    int initTot = H1 * H2 + H2 * H3;
    if (initTot < N) initTot = N;
    k_init_wt<<<cdiv(initTot, 256), 256, 0, stream>>>(dinv, cnt, cursor, N,
                                                      W2, WT2, H1, H2, W3, WT3, H2, H3);
    k_hist_deg<<<cdiv(E, 256), 256, 0, stream>>>(dstv, ew, dinv, cnt, E);
    int nb = cdiv(N, 1024);
    k_dinv_scana<<<nb, 256, 0, stream>>>(dinv, cnt, bsum, N);
    k_scan_c<<<nb, 256, 0, stream>>>(cnt, bsum, row_start, N, nb);
    k_scatter_norm<<<cdiv(E, 256), 256, 0, stream>>>(srcv, dstv, ew, dinv, row_start,
                                                     cursor, esrc, enorm, E);

    // ---- layer 1: fused agg + fp32 GEMM -> h1 bf16 [N,128]
    k_l1_gemm<<<cdiv(N, 128), 256, 0, stream>>>(x, dinv, esrc, enorm, row_start, W1, b1, h1, N);

    // ---- layer 2: agg(h1 bf16) -> Abf -> MFMA GEMM -> h2 bf16 [N,256]
    k_agg_bf<<<cdiv(Mpad * (H1 / 8), 256), 256, 0, stream>>>(
        h1, dinv, esrc, enorm, row_start, Abf, N, Mpad, H1, __builtin_ctz(H1) - 3);
    k_gemm_async<0><<<(Mpad / 128) * (H2 / 128), 256, 0, stream>>>(
        Abf, WT2, b2, h2, nullptr, nullptr, N, Mpad, H1, H2, __builtin_ctz(H2 / 128));

    // ---- layer 3: agg(h2 bf16) -> Abf -> MFMA GEMM + fused FC dot -> part
    k_agg_bf<<<cdiv(Mpad * (H2 / 8), 256), 256, 0, stream>>>(
        h2, dinv, esrc, enorm, row_start, Abf, N, Mpad, H2, __builtin_ctz(H2) - 3);
    k_gemm_async<1><<<(Mpad / 128) * (H3 / 128), 256, 0, stream>>>(
        Abf, WT3, b3, nullptr, Wfc, part, N, Mpad, H2, H3, __builtin_ctz(H3 / 128));

    // ---- pool: segment mean of summed partials + sigmoid
    k_pool2<<<cdiv(G * 64, 256), 256, 0, stream>>>(part, bat, bfc, out, N, Mpad, H3 / 128, G);
}

// Round 13
// 212.283 us; speedup vs baseline: 1.4222x; 1.0265x over previous
//
#include <hip/hip_runtime.h>
#include <math.h>

typedef __attribute__((ext_vector_type(8))) short short8;
typedef __attribute__((ext_vector_type(4))) float floatx4;

// ---------------- bf16 helpers ----------------

__device__ __forceinline__ unsigned short f2bf(float f) {
    unsigned int u = __float_as_uint(f);
    unsigned int r = (u + 0x7fffu + ((u >> 16) & 1u)) >> 16;  // RNE
    return (unsigned short)r;
}
__device__ __forceinline__ float bfu_lo(unsigned int u) {
    return __uint_as_float(u << 16);
}
__device__ __forceinline__ float bfu_hi(unsigned int u) {
    return __uint_as_float(u & 0xffff0000u);
}

// ---------------- precompute ----------------

// init deg/cnt/cursor + both weight transposes (one launch)
__global__ void k_init_wt(float* __restrict__ deg, int* __restrict__ cnt,
                          int* __restrict__ cursor, int N,
                          const float* __restrict__ W2, unsigned short* __restrict__ WT2,
                          int K2, int F2,
                          const float* __restrict__ W3, unsigned short* __restrict__ WT3,
                          int K3, int F3) {
    int i = blockIdx.x * blockDim.x + threadIdx.x;
    if (i < N) { deg[i] = 1.0f; cnt[i] = 0; cursor[i] = 0; }
    int n2 = K2 * F2;
    if (i < n2) {
        int k = i / F2, n = i % F2;
        WT2[(size_t)n * K2 + k] = f2bf(W2[i]);
    } else {
        int j = i - n2;
        if (j < K3 * F3) {
            int k = j / F3, n = j % F3;
            WT3[(size_t)n * K3 + k] = f2bf(W3[j]);
        }
    }
}

__global__ void k_hist_deg(const int* __restrict__ dst, const float* __restrict__ ew,
                           float* __restrict__ deg, int* __restrict__ cnt, int E) {
    int e = blockIdx.x * blockDim.x + threadIdx.x;
    if (e < E) {
        int d = dst[e];
        atomicAdd(&deg[d], ew[e]);
        atomicAdd(&cnt[d], 1);
    }
}

// fused: deg -> rsqrt in place (dinv) AND per-block cnt sums for the scan
__global__ __launch_bounds__(256) void k_dinv_scana(float* __restrict__ deg,
                                                    const int* __restrict__ cnt,
                                                    int* __restrict__ bsum, int N) {
    int b = blockIdx.x, t = threadIdx.x;
    int base = b * 1024 + t * 4;
    int s = 0;
#pragma unroll
    for (int j = 0; j < 4; ++j) {
        int i = base + j;
        if (i < N) { deg[i] = rsqrtf(deg[i]); s += cnt[i]; }
    }
    __shared__ int sh[256];
    sh[t] = s; __syncthreads();
    for (int st = 128; st > 0; st >>= 1) { if (t < st) sh[t] += sh[t + st]; __syncthreads(); }
    if (t == 0) bsum[b] = sh[0];
}

// scan_c with inlined cross-block offset
__global__ __launch_bounds__(256) void k_scan_c(const int* __restrict__ cnt,
                                                const int* __restrict__ bsum,
                                                int* __restrict__ row_start, int N, int nb) {
    int b = blockIdx.x, t = threadIdx.x;
    __shared__ int sh[256];
    __shared__ int boffs;

    if (t < 64) {
        int s = 0;
        for (int i = t; i < b; i += 64) s += bsum[i];
#pragma unroll
        for (int off = 32; off > 0; off >>= 1) s += __shfl_down(s, off);
        if (t == 0) boffs = s;
    }
    __syncthreads();

    int base = b * 1024 + t * 4;
    int v[4]; int s = 0;
#pragma unroll
    for (int j = 0; j < 4; ++j) { int i = base + j; v[j] = (i < N) ? cnt[i] : 0; s += v[j]; }
    sh[t] = s; __syncthreads();
    for (int off = 1; off < 256; off <<= 1) {
        int x = (t >= off) ? sh[t - off] : 0;
        __syncthreads();
        sh[t] += x;
        __syncthreads();
    }
    int excl = sh[t] - s + boffs;
#pragma unroll
    for (int j = 0; j < 4; ++j) {
        int i = base + j;
        if (i < N) row_start[i] = excl;
        excl += v[j];
        if (i == N - 1) row_start[N] = excl;
    }
}

// fused: CSR scatter + norm computation
__global__ void k_scatter_norm(const int* __restrict__ src, const int* __restrict__ dst,
                               const float* __restrict__ ew, const float* __restrict__ dinv,
                               const int* __restrict__ row_start, int* __restrict__ cursor,
                               int* __restrict__ esrc, float* __restrict__ enorm, int E) {
    int e = blockIdx.x * blockDim.x + threadIdx.x;
    if (e >= E) return;
    int d = dst[e], s = src[e];
    int pos = row_start[d] + atomicAdd(&cursor[d], 1);
    esrc[pos] = s;
    enorm[pos] = dinv[s] * ew[e] * dinv[d];
}

// ---------------- layer 1: fused agg(x)[N,8] + fp32 GEMM(K=8) -> relu -> h1 bf16 ----------------
// Gather phase uses all 256 threads: 2 threads per node, 4 feats each.

__global__ __launch_bounds__(256) void k_l1_gemm(
    const float* __restrict__ x, const float* __restrict__ dinv,
    const int* __restrict__ esrc, const float* __restrict__ enorm,
    const int* __restrict__ row_start, const float* __restrict__ W1,
    const float* __restrict__ b1, unsigned short* __restrict__ h1, int N) {
    __shared__ float As[8][132];
    __shared__ float Bs[8][128];

    int tid = threadIdx.x;
    int bm = blockIdx.x * 128;

#pragma unroll
    for (int i = tid; i < 1024; i += 256) Bs[i >> 7][i & 127] = W1[i];

    {
        int node = tid >> 1;          // 0..127
        int half = tid & 1;           // which 4 features
        int n = bm + node;
        float a[4] = {0, 0, 0, 0};
        if (n < N) {
            float dv = dinv[n];
            float dv2 = dv * dv;
            float4 v0 = *(const float4*)&x[(size_t)n * 8 + half * 4];
            a[0] = v0.x * dv2; a[1] = v0.y * dv2; a[2] = v0.z * dv2; a[3] = v0.w * dv2;
            int j0 = row_start[n], j1 = row_start[n + 1];
            // 4-wide MLP gather: 4 independent row loads in flight
            for (int b = j0; b < j1; b += 4) {
                int i1 = (b + 1 < j1) ? b + 1 : b;
                int i2 = (b + 2 < j1) ? b + 2 : b;
                int i3 = (b + 3 < j1) ? b + 3 : b;
                float w0 = enorm[b];
                float w1 = (b + 1 < j1) ? enorm[i1] : 0.f;
                float w2 = (b + 2 < j1) ? enorm[i2] : 0.f;
                float w3 = (b + 3 < j1) ? enorm[i3] : 0.f;
                int s0 = esrc[b], s1 = esrc[i1], s2 = esrc[i2], s3 = esrc[i3];
                float4 p0 = *(const float4*)&x[(size_t)s0 * 8 + half * 4];
                float4 p1 = *(const float4*)&x[(size_t)s1 * 8 + half * 4];
                float4 p2 = *(const float4*)&x[(size_t)s2 * 8 + half * 4];
                float4 p3 = *(const float4*)&x[(size_t)s3 * 8 + half * 4];
                a[0] += w0 * p0.x + w1 * p1.x + w2 * p2.x + w3 * p3.x;
                a[1] += w0 * p0.y + w1 * p1.y + w2 * p2.y + w3 * p3.y;
                a[2] += w0 * p0.z + w1 * p1.z + w2 * p2.z + w3 * p3.z;
                a[3] += w0 * p0.w + w1 * p1.w + w2 * p2.w + w3 * p3.w;
            }
        }
#pragma unroll
        for (int k = 0; k < 4; ++k) As[half * 4 + k][node] = a[k];
    }
    __syncthreads();

    int tx = tid & 15;
    int ty = tid >> 4;
    float acc[8][8];
#pragma unroll
    for (int i = 0; i < 8; ++i)
#pragma unroll
        for (int j = 0; j < 8; ++j) acc[i][j] = 0.f;

#pragma unroll
    for (int k = 0; k < 8; ++k) {
        float a[8], b[8];
        float4 a0 = *(const float4*)&As[k][ty * 4];
        float4 a1 = *(const float4*)&As[k][ty * 4 + 64];
        float4 b0 = *(const float4*)&Bs[k][tx * 4];
        float4 b1 = *(const float4*)&Bs[k][tx * 4 + 64];
        a[0] = a0.x; a[1] = a0.y; a[2] = a0.z; a[3] = a0.w;
        a[4] = a1.x; a[5] = a1.y; a[6] = a1.z; a[7] = a1.w;
        b[0] = b0.x; b[1] = b0.y; b[2] = b0.z; b[3] = b0.w;
        b[4] = b1.x; b[5] = b1.y; b[6] = b1.z; b[7] = b1.w;
#pragma unroll
        for (int i = 0; i < 8; ++i)
#pragma unroll
            for (int j = 0; j < 8; ++j) acc[i][j] += a[i] * b[j];
    }

    float4 bi0 = *(const float4*)&b1[tx * 4];
    float4 bi1 = *(const float4*)&b1[tx * 4 + 64];
    float bb[8] = {bi0.x, bi0.y, bi0.z, bi0.w, bi1.x, bi1.y, bi1.z, bi1.w};
#pragma unroll
    for (int i = 0; i < 8; ++i) {
        int gm = bm + ((i < 4) ? (ty * 4 + i) : (64 + ty * 4 + i - 4));
        if (gm >= N) continue;
        ushort4 v0, v1;
        v0.x = f2bf(fmaxf(acc[i][0] + bb[0], 0.f));
        v0.y = f2bf(fmaxf(acc[i][1] + bb[1], 0.f));
        v0.z = f2bf(fmaxf(acc[i][2] + bb[2], 0.f));
        v0.w = f2bf(fmaxf(acc[i][3] + bb[3], 0.f));
        v1.x = f2bf(fmaxf(acc[i][4] + bb[4], 0.f));
        v1.y = f2bf(fmaxf(acc[i][5] + bb[5], 0.f));
        v1.z = f2bf(fmaxf(acc[i][6] + bb[6], 0.f));
        v1.w = f2bf(fmaxf(acc[i][7] + bb[7], 0.f));
        *(ushort4*)&h1[(size_t)gm * 128 + tx * 4] = v0;
        *(ushort4*)&h1[(size_t)gm * 128 + tx * 4 + 64] = v1;
    }
}

// ---------------- aggregation, bf16 in -> bf16 out, 8 feats/thread, 4-wide MLP gather ----------------

__global__ void k_agg_bf(const unsigned short* __restrict__ h, const float* __restrict__ dinv,
                         const int* __restrict__ esrc, const float* __restrict__ enorm,
                         const int* __restrict__ row_start,
                         unsigned short* __restrict__ A,
                         int N, int Mpad, int F, int osh) {
    int p = blockIdx.x * blockDim.x + threadIdx.x;
    int oct = F >> 3;
    if (p >= Mpad * oct) return;
    int n = p >> osh;
    int fo = (p & (oct - 1)) << 3;
    size_t oidx = (size_t)n * F + fo;
    if (n >= N) {
        *(uint4*)&A[oidx] = make_uint4(0, 0, 0, 0);
        return;
    }
    float dv = dinv[n];
    float dv2 = dv * dv;
    uint4 hv = *(const uint4*)&h[oidx];
    float s0 = bfu_lo(hv.x) * dv2, s1 = bfu_hi(hv.x) * dv2;
    float s2 = bfu_lo(hv.y) * dv2, s3 = bfu_hi(hv.y) * dv2;
    float s4 = bfu_lo(hv.z) * dv2, s5 = bfu_hi(hv.z) * dv2;
    float s6 = bfu_lo(hv.w) * dv2, s7 = bfu_hi(hv.w) * dv2;
    int j0 = row_start[n], j1 = row_start[n + 1];
    for (int b = j0; b < j1; b += 4) {
        int i1 = (b + 1 < j1) ? b + 1 : b;
        int i2 = (b + 2 < j1) ? b + 2 : b;
        int i3 = (b + 3 < j1) ? b + 3 : b;
        float w0 = enorm[b];
        float w1 = (b + 1 < j1) ? enorm[i1] : 0.f;
        float w2 = (b + 2 < j1) ? enorm[i2] : 0.f;
        float w3 = (b + 3 < j1) ? enorm[i3] : 0.f;
        int e0 = esrc[b], e1 = esrc[i1], e2 = esrc[i2], e3 = esrc[i3];
        uint4 r0 = *(const uint4*)&h[(size_t)e0 * F + fo];
        uint4 r1 = *(const uint4*)&h[(size_t)e1 * F + fo];
        uint4 r2 = *(const uint4*)&h[(size_t)e2 * F + fo];
        uint4 r3 = *(const uint4*)&h[(size_t)e3 * F + fo];
        s0 += w0 * bfu_lo(r0.x) + w1 * bfu_lo(r1.x) + w2 * bfu_lo(r2.x) + w3 * bfu_lo(r3.x);
        s1 += w0 * bfu_hi(r0.x) + w1 * bfu_hi(r1.x) + w2 * bfu_hi(r2.x) + w3 * bfu_hi(r3.x);
        s2 += w0 * bfu_lo(r0.y) + w1 * bfu_lo(r1.y) + w2 * bfu_lo(r2.y) + w3 * bfu_lo(r3.y);
        s3 += w0 * bfu_hi(r0.y) + w1 * bfu_hi(r1.y) + w2 * bfu_hi(r2.y) + w3 * bfu_hi(r3.y);
        s4 += w0 * bfu_lo(r0.z) + w1 * bfu_lo(r1.z) + w2 * bfu_lo(r2.z) + w3 * bfu_lo(r3.z);
        s5 += w0 * bfu_hi(r0.z) + w1 * bfu_hi(r1.z) + w2 * bfu_hi(r2.z) + w3 * bfu_hi(r3.z);
        s6 += w0 * bfu_lo(r0.w) + w1 * bfu_lo(r1.w) + w2 * bfu_lo(r2.w) + w3 * bfu_lo(r3.w);
        s7 += w0 * bfu_hi(r0.w) + w1 * bfu_hi(r1.w) + w2 * bfu_hi(r2.w) + w3 * bfu_hi(r3.w);
    }
    uint4 o;
    o.x = (unsigned int)f2bf(s0) | ((unsigned int)f2bf(s1) << 16);
    o.y = (unsigned int)f2bf(s2) | ((unsigned int)f2bf(s3) << 16);
    o.z = (unsigned int)f2bf(s4) | ((unsigned int)f2bf(s5) << 16);
    o.w = (unsigned int)f2bf(s6) | ((unsigned int)f2bf(s7) << 16);
    *(uint4*)&A[oidx] = o;
}

// ---------------- bf16 MFMA GEMM, BK=64 double-staged async LDS, XCD swizzle ----------------
// Per k0 iteration: stage 4 sub-tiles (A/B x 2 k-slices of 32) = 32 KB, ONE barrier,
// two MFMA sub-steps. Halves barrier-drain count vs BK=32.
// EPI=0: C = relu(A@W+bias) bf16. EPI=1: fused FC dot -> part[bnIdx*Mpad+row].

template <int EPI>
__global__ __launch_bounds__(256, 4) void k_gemm_async(
    const unsigned short* __restrict__ A, const unsigned short* __restrict__ B,
    const float* __restrict__ bias, unsigned short* __restrict__ C,
    const float* __restrict__ Wfc, float* __restrict__ part,
    int M, int Mpad, int K, int Fout, int nbsh) {
    __shared__ __align__(16) unsigned short smem[16384];  // 32 KB: A0,A1,B0,B1 sub-tiles

    int tid = threadIdx.x, wave = tid >> 6, lane = tid & 63;
    int quad = lane >> 4, r = lane & 15;

    // XCD swizzle: all bn-blocks of one bm-group land on the same XCD
    int P = blockIdx.x;
    int r8 = P & 7;
    int q = P >> 3;
    int bnIdx = q & ((1 << nbsh) - 1);
    int g = ((q >> nbsh) << 3) + r8;
    int bm = g * 128, bn = bnIdx * 128;
    int wm = (wave & 1) * 64, wn = (wave >> 1) * 64;

    const unsigned short* gsrc[2] = {A, B};
    const int rb[2] = {bm, bn};

    floatx4 acc[4][4] = {};

    for (int k0 = 0; k0 < K; k0 += 64) {
        // stage 4 sub-tiles (128 rows x 32 bf16 each): (A,w0),(A,w1),(B,w0),(B,w1)
#pragma unroll
        for (int t = 0; t < 2; ++t) {
#pragma unroll
            for (int w = 0; w < 2; ++w) {
#pragma unroll
                for (int i = 0; i < 2; ++i) {
                    int qc = wave * 2 + i;
                    int idx = qc * 64 + lane;
                    int row = idx >> 2, kofs = (idx & 3) << 3;
                    const unsigned short* gptr =
                        gsrc[t] + ((size_t)(rb[t] + row) * K + k0 + w * 32 + kofs);
                    unsigned short* l = &smem[(t * 2 + w) * 4096 + qc * 512];
                    __builtin_amdgcn_global_load_lds(
                        (const __attribute__((address_space(1))) void*)gptr,
                        (__attribute__((address_space(3))) void*)l, 16, 0, 0);
                }
            }
        }
        __syncthreads();

#pragma unroll
        for (int w = 0; w < 2; ++w) {
            short8 ah[4];
#pragma unroll
            for (int mt = 0; mt < 4; ++mt) {
                int m = wm + mt * 16 + r;
                ah[mt] = *(const short8*)&smem[w * 4096 + m * 32 + quad * 8];
            }
#pragma unroll
            for (int nt = 0; nt < 4; ++nt) {
                int n = wn + nt * 16 + r;
                short8 bh = *(const short8*)&smem[(2 + w) * 4096 + n * 32 + quad * 8];
#pragma unroll
                for (int mt = 0; mt < 4; ++mt)
                    acc[mt][nt] =
                        __builtin_amdgcn_mfma_f32_16x16x32_bf16(ah[mt], bh, acc[mt][nt], 0, 0, 0);
            }
        }
        __syncthreads();
    }

    float bv[4];
#pragma unroll
    for (int nt = 0; nt < 4; ++nt) bv[nt] = bias[bn + wn + nt * 16 + r];

    if (EPI == 0) {
        float* eps = (float*)&smem[0] + wave * 1024;
#pragma unroll
        for (int mt = 0; mt < 4; ++mt) {
#pragma unroll
            for (int nt = 0; nt < 4; ++nt)
#pragma unroll
                for (int reg = 0; reg < 4; ++reg)
                    eps[(quad * 4 + reg) * 64 + nt * 16 + r] =
                        fmaxf(acc[mt][nt][reg] + bv[nt], 0.f);
#pragma unroll
            for (int i = 0; i < 4; ++i) {
                int fl = i * 64 + lane;
                int ri = fl >> 4, c4 = fl & 15;
                float4 v = *(const float4*)&eps[ri * 64 + c4 * 4];
                int gm = bm + wm + mt * 16 + ri;
                if (gm < M)
                    *(ushort4*)&C[(size_t)gm * Fout + bn + wn + c4 * 4] =
                        make_ushort4(f2bf(v.x), f2bf(v.y), f2bf(v.z), f2bf(v.w));
            }
        }
    } else {
        float* rowsum = (float*)&smem[0];
        if (tid < 128) rowsum[tid] = 0.f;
        __syncthreads();
        float wf[4];
#pragma unroll
        for (int nt = 0; nt < 4; ++nt) wf[nt] = Wfc[bn + wn + nt * 16 + r];
#pragma unroll
        for (int mt = 0; mt < 4; ++mt)
#pragma unroll
            for (int reg = 0; reg < 4; ++reg) {
                float v = 0.f;
#pragma unroll
                for (int nt = 0; nt < 4; ++nt)
                    v += fmaxf(acc[mt][nt][reg] + bv[nt], 0.f) * wf[nt];
                v += __shfl_xor(v, 1);
                v += __shfl_xor(v, 2);
                v += __shfl_xor(v, 4);
                v += __shfl_xor(v, 8);
                if (r == 0) atomicAdd(&rowsum[wm + mt * 16 + quad * 4 + reg], v);
            }
        __syncthreads();
        if (tid < 128) part[(size_t)bnIdx * Mpad + bm + tid] = rowsum[tid];
    }
}

// ---------------- pool: sum partials; segment mean + sigmoid ----------------

__global__ __launch_bounds__(256) void k_pool2(const float* __restrict__ part,
                                               const int* __restrict__ batch,
                                               const float* __restrict__ bfc,
                                               float* __restrict__ out,
                                               int N, int Mpad, int nchunks, int G) {
    int g = (int)((blockIdx.x * blockDim.x + threadIdx.x) >> 6);
    int lane = threadIdx.x & 63;
    if (g >= G) return;
    int lo = 0, hi = N;
    while (lo < hi) { int m = (lo + hi) >> 1; if (batch[m] < g) lo = m + 1; else hi = m; }
    int start = lo;
    hi = N;
    while (lo < hi) { int m = (lo + hi) >> 1; if (batch[m] < g + 1) lo = m + 1; else hi = m; }
    int end = lo;
    float s = 0.f;
    for (int i = start + lane; i < end; i += 64) {
        float t = 0.f;
        for (int c = 0; c < nchunks; ++c) t += part[(size_t)c * Mpad + i];
        s += t;
    }
#pragma unroll
    for (int off = 32; off > 0; off >>= 1) s += __shfl_down(s, off);
    if (lane == 0) {
        float c = (float)(end - start);
        if (c < 1.f) c = 1.f;
        float z = s / c + bfc[0];
        out[g] = 1.f / (1.f + expf(-z));
    }
}

// ---------------- launcher ----------------

static inline int cdiv(int a, int b) { return (a + b - 1) / b; }

extern "C" void kernel_launch(void* const* d_in, const int* in_sizes, int n_in,
                              void* d_out, int out_size, void* d_ws, size_t ws_size,
                              hipStream_t stream) {
    const float* x   = (const float*)d_in[0];
    const int*   ei  = (const int*)d_in[1];
    const float* ew  = (const float*)d_in[2];
    const int*   bat = (const int*)d_in[3];
    const float* W1  = (const float*)d_in[4];
    const float* b1  = (const float*)d_in[5];
    const float* W2  = (const float*)d_in[6];
    const float* b2  = (const float*)d_in[7];
    const float* W3  = (const float*)d_in[8];
    const float* b3  = (const float*)d_in[9];
    const float* Wfc = (const float*)d_in[10];
    const float* bfc = (const float*)d_in[11];
    float* out = (float*)d_out;

    const int N  = in_sizes[3];
    const int E  = in_sizes[2];
    const int H1 = in_sizes[5];       // 128
    const int H2 = in_sizes[7];       // 256
    const int H3 = in_sizes[9];       // 512
    const int G  = out_size;          // 256
    const int Mpad = cdiv(N, 1024) * 1024;  // /128 divisible by 8 (XCD swizzle)
    const int Npad4 = (N + 4) & ~3;

    const int* srcv = ei;
    const int* dstv = ei + E;

    char* p = (char*)d_ws;
    float* dinv      = (float*)p; p += (size_t)N * 4;   // deg, then rsqrt in place
    int*   cnt       = (int*)p;   p += (size_t)N * 4;
    int*   cursor    = (int*)p;   p += (size_t)N * 4;
    int*   bsum      = (int*)p;   p += 256 * 4;
    int*   row_start = (int*)p;   p += (size_t)Npad4 * 4;
    int*   esrc      = (int*)p;   p += (size_t)E * 4;
    float* enorm     = (float*)p; p += (size_t)E * 4;
    float* part      = (float*)p; p += (size_t)(H3 / 128) * Mpad * 4;
    unsigned short* WT2 = (unsigned short*)p; p += (size_t)H1 * H2 * 2;
    unsigned short* WT3 = (unsigned short*)p; p += (size_t)H2 * H3 * 2;
    unsigned short* Abf = (unsigned short*)p; p += (size_t)Mpad * H2 * 2;
    unsigned short* h1  = (unsigned short*)p; p += (size_t)Mpad * H1 * 2;
    unsigned short* h2  = (unsigned short*)p; p += (size_t)Mpad * H2 * 2;

    // ---- precompute (5 launches, no grid sync, no device fences)
    int initTot = H1 * H2 + H2 * H3;
    if (initTot < N) initTot = N;
    k_init_wt<<<cdiv(initTot, 256), 256, 0, stream>>>(dinv, cnt, cursor, N,
                                                      W2, WT2, H1, H2, W3, WT3, H2, H3);
    k_hist_deg<<<cdiv(E, 256), 256, 0, stream>>>(dstv, ew, dinv, cnt, E);
    int nb = cdiv(N, 1024);
    k_dinv_scana<<<nb, 256, 0, stream>>>(dinv, cnt, bsum, N);
    k_scan_c<<<nb, 256, 0, stream>>>(cnt, bsum, row_start, N, nb);
    k_scatter_norm<<<cdiv(E, 256), 256, 0, stream>>>(srcv, dstv, ew, dinv, row_start,
                                                     cursor, esrc, enorm, E);

    // ---- layer 1: fused agg + fp32 GEMM -> h1 bf16 [N,128]
    k_l1_gemm<<<cdiv(N, 128), 256, 0, stream>>>(x, dinv, esrc, enorm, row_start, W1, b1, h1, N);

    // ---- layer 2: agg(h1 bf16) -> Abf -> MFMA GEMM -> h2 bf16 [N,256]
    k_agg_bf<<<cdiv(Mpad * (H1 / 8), 256), 256, 0, stream>>>(
        h1, dinv, esrc, enorm, row_start, Abf, N, Mpad, H1, __builtin_ctz(H1) - 3);
    k_gemm_async<0><<<(Mpad / 128) * (H2 / 128), 256, 0, stream>>>(
        Abf, WT2, b2, h2, nullptr, nullptr, N, Mpad, H1, H2, __builtin_ctz(H2 / 128));

    // ---- layer 3: agg(h2 bf16) -> Abf -> MFMA GEMM + fused FC dot -> part
    k_agg_bf<<<cdiv(Mpad * (H2 / 8), 256), 256, 0, stream>>>(
        h2, dinv, esrc, enorm, row_start, Abf, N, Mpad, H2, __builtin_ctz(H2) - 3);
    k_gemm_async<1><<<(Mpad / 128) * (H3 / 128), 256, 0, stream>>>(
        Abf, WT3, b3, nullptr, Wfc, part, N, Mpad, H2, H3, __builtin_ctz(H3 / 128));

    // ---- pool: segment mean of summed partials + sigmoid
    k_pool2<<<cdiv(G * 64, 256), 256, 0, stream>>>(part, bat, bfc, out, N, Mpad, H3 / 128, G);
}